// Round 9
// baseline (375.288 us; speedup 1.0000x reference)
//
#include <hip/hip_runtime.h>
#include <cmath>

// ---------------------------------------------------------------- types
typedef __bf16 bf16x8 __attribute__((ext_vector_type(8)));
typedef __bf16 bf16x4 __attribute__((ext_vector_type(4)));
typedef float  floatx4 __attribute__((ext_vector_type(4)));

#define LN_EPS 1e-5f
#define INV_TEMP 0.125f   // 1/sqrt(64)

// B=32 S=512 D=512 H=8 DK=DV=64 DFF=2048, M = B*S = 16384
static const int Mrows = 16384;

__device__ __forceinline__ void gload_lds16(const void* g, void* l) {
  __builtin_amdgcn_global_load_lds(
      (const __attribute__((address_space(1))) void*)g,
      (__attribute__((address_space(3))) void*)l, 16, 0, 0);
}

// ---------------------------------------------------------------- fused prep: x->bf16 + 6 weight transposes
__global__ __launch_bounds__(256) void prep_kernel(const float* __restrict__ x, __bf16* __restrict__ xb,
                                                   const float* __restrict__ wq, const float* __restrict__ wk,
                                                   const float* __restrict__ wv, const float* __restrict__ wo,
                                                   const float* __restrict__ wff1, const float* __restrict__ wff2,
                                                   __bf16* __restrict__ tq, __bf16* __restrict__ tk,
                                                   __bf16* __restrict__ tv, __bf16* __restrict__ to_,
                                                   __bf16* __restrict__ tff1, __bf16* __restrict__ tff2) {
  const int bid = blockIdx.x, tid = threadIdx.x;
  if (bid < 8192) {
    int i = bid * 256 + tid;
    float4 v = ((const float4*)x)[i];
    __bf16* d = xb + i * 4;
    d[0] = (__bf16)v.x; d[1] = (__bf16)v.y; d[2] = (__bf16)v.z; d[3] = (__bf16)v.w;
    return;
  }
  __shared__ __bf16 til[64][72];
  int t = bid - 8192;
  const float* src; __bf16* dst; int R, C, bx, by;
  if (t < 256) {
    int w = t >> 6, tt = t & 63;
    const float* srcs[4] = {wq, wk, wv, wo};
    __bf16* dsts[4] = {tq, tk, tv, to_};
    src = srcs[w]; dst = dsts[w]; R = 512; C = 512; bx = tt & 7; by = tt >> 3;
  } else if (t < 512) {
    int tt = t - 256;
    src = wff1; dst = tff1; R = 512; C = 2048; bx = tt & 31; by = tt >> 5;
  } else {
    int tt = t - 512;
    src = wff2; dst = tff2; R = 2048; C = 512; bx = tt & 7; by = tt >> 3;
  }
  const float* s = src + (size_t)(by * 64) * C + bx * 64;
  int r = tid >> 4, c4 = (tid & 15) * 4;
  for (int p = 0; p < 4; ++p) {
    int rr = r + p * 16;
    float4 v = *(const float4*)(s + (size_t)rr * C + c4);
    til[c4 + 0][rr] = (__bf16)v.x;
    til[c4 + 1][rr] = (__bf16)v.y;
    til[c4 + 2][rr] = (__bf16)v.z;
    til[c4 + 3][rr] = (__bf16)v.w;
  }
  __syncthreads();
  __bf16* d = dst + (size_t)(bx * 64) * R + by * 64;
  int orow = tid >> 3, oc8 = (tid & 7) * 8;
  for (int p = 0; p < 2; ++p) {
    int rr = orow + p * 32;
    *(bf16x8*)(d + (size_t)rr * R + oc8) = *(const bf16x8*)(&til[rr][oc8]);
  }
}

// ---------------------------------------------------------------- GEMM  C = A[M,K] * Bt[N,K]^T -> bf16
// MT=1: 128x128 block, 64x64 wave (R7-identical). MT=2: 256x128 block, 128x64 wave
// (0.375 LDS reads/MFMA vs 0.5; half the barriers per output).
// BK=64, 128B LDS rows, 16B-slot XOR swizzle. Epilogue via padded LDS -> b128 stores.
// EPI: 0 plain, 2 +bias,relu, 4 QKV (fused inverse q/k norms + V-transpose into vtg)
template <int EPI, int MT, int NBN, int NDIM, int KDIM>
__global__ __launch_bounds__(256) void gemm_bt(const __bf16* __restrict__ A,
                                               const __bf16* __restrict__ Bt,
                                               __bf16* __restrict__ Cv,
                                               const float* __restrict__ bias,
                                               float* __restrict__ norms,
                                               __bf16* __restrict__ vtg) {
  constexpr int AS_ELEMS = MT * 8192;                 // A tile MT*128 x 64
  constexpr int SM_ELEMS = (AS_ELEMS + 8192 > 18432) ? (AS_ELEMS + 8192) : 18432;
  __shared__ __align__(16) __bf16 smem[SM_ELEMS];
  __bf16* As = smem;
  __bf16* Bs = smem + AS_ELEMS;
  const int tid = threadIdx.x;
  const int wave = tid >> 6, lane = tid & 63;
  const int l15 = lane & 15, quad = lane >> 4;
  const int id = blockIdx.x;
  const int xcd = id & 7, t = id >> 3;
  const int nblk = t % NBN, mblk = (t / NBN) * 8 + xcd;
  const int m0 = mblk * (MT * 128), n0 = nblk * 128;
  const int wrow = (wave >> 1) * (MT * 64), wcol = (wave & 1) * 64;
  const int rs = lane >> 3;
  const int swz_st = ((lane & 7) ^ rs) * 8;
  const int s7 = l15 & 7;

  floatx4 zero = {0.f, 0.f, 0.f, 0.f};
  floatx4 acc[MT * 4][4];
#pragma unroll
  for (int i = 0; i < MT * 4; ++i)
#pragma unroll
    for (int j = 0; j < 4; ++j) acc[i][j] = zero;

  for (int kt = 0; kt < KDIM; kt += 64) {
    __syncthreads();
    constexpr int CPW = MT * 4 + 4;   // staging chunks per wave
#pragma unroll
    for (int c = 0; c < CPW; ++c) {
      int g = wave * CPW + c;
      const __bf16* src;
      __bf16* dst;
      if (g < MT * 16) {
        int row = m0 + g * 8 + rs;
        src = A + (size_t)row * KDIM + kt + swz_st;
        dst = As + g * 512;
      } else {
        int g2 = g - MT * 16;
        int row = n0 + g2 * 8 + rs;
        src = Bt + (size_t)row * KDIM + kt + swz_st;
        dst = Bs + g2 * 512;
      }
      gload_lds16(src, dst + lane * 8);
    }
    __syncthreads();
#pragma unroll
    for (int hh = 0; hh < 2; ++hh) {
      int ko = ((hh * 4 + quad) ^ s7) * 8;
      bf16x8 a[MT * 4], b[4];
#pragma unroll
      for (int i = 0; i < MT * 4; ++i)
        a[i] = *(const bf16x8*)(As + (wrow + i * 16 + l15) * 64 + ko);
#pragma unroll
      for (int j = 0; j < 4; ++j)
        b[j] = *(const bf16x8*)(Bs + (wcol + j * 16 + l15) * 64 + ko);
#pragma unroll
      for (int i = 0; i < MT * 4; ++i)
#pragma unroll
        for (int j = 0; j < 4; ++j)
          acc[i][j] = __builtin_amdgcn_mfma_f32_16x16x32_bf16(a[i], b[j], acc[i][j], 0, 0, 0);
    }
  }

  if constexpr (EPI == 4) {
    int head_global = (n0 + wcol) >> 6;
    int kind = head_global >> 3;          // 0=q 1=k 2=v (uniform per block: 128-col tiles)
    if (kind < 2) {
      // fused INVERSE q/k norms
      int h = head_global & 7;
#pragma unroll
      for (int i = 0; i < MT * 4; ++i)
#pragma unroll
        for (int r = 0; r < 4; ++r) {
          float sq = 0.f;
#pragma unroll
          for (int j = 0; j < 4; ++j) {
            float v = acc[i][j][r];
            sq += v * v;
          }
          for (int m = 1; m < 16; m <<= 1) sq += __shfl_xor(sq, m, 64);
          if (l15 == 0) {
            int arow = m0 + wrow + i * 16 + quad * 4 + r;
            int bb = arow >> 9, ss = arow & 511;
            norms[kind * 131072 + ((bb << 3) + h) * 512 + ss] = rsqrtf(sq);
          }
        }
    } else {
      // v-tile: transpose through LDS straight into vtg[bh][d][s], MT halves
      const int bb2 = (MT == 2) ? (mblk >> 1) : (mblk >> 2);
      const int s0r = (MT == 2) ? ((mblk & 1) * 256) : ((mblk & 3) * 128);
      for (int half = 0; half < MT; ++half) {
        __syncthreads();
        if (MT == 1 || (wave >> 1) == half) {
          int rbase = (MT == 1) ? wrow : 0;
#pragma unroll
          for (int i = 0; i < MT * 4; ++i)
#pragma unroll
            for (int j = 0; j < 4; ++j) {
              bf16x4 pk;
#pragma unroll
              for (int r = 0; r < 4; ++r) pk[r] = (__bf16)acc[i][j][r];
              *(bf16x4*)(smem + (wcol + j * 16 + l15) * 144 + rbase + i * 16 + quad * 4) = pk;
            }
        }
        __syncthreads();
        for (int p = 0; p < 8; ++p) {
          int row = p * 16 + (tid >> 4);    // local n-col (d)
          int c8 = (tid & 15) * 8;          // local m (s)
          int colg = n0 + row;
          int h = (colg >> 6) & 7, d = colg & 63;
          *(bf16x8*)(vtg + ((size_t)(((bb2 << 3) + h) * 64 + d)) * 512 + s0r + half * 128 + c8) =
              *(const bf16x8*)(smem + row * 144 + c8);
        }
      }
      return;
    }
  }

  // normal epilogue: acc -> padded LDS tile (per 128-row half) -> wide stores
  for (int half = 0; half < MT; ++half) {
    __syncthreads();
    if (MT == 1 || (wave >> 1) == half) {
      int rbase = (MT == 1) ? wrow : 0;
#pragma unroll
      for (int i = 0; i < MT * 4; ++i)
#pragma unroll
        for (int j = 0; j < 4; ++j) {
          int coll = wcol + j * 16 + l15;
          float bv = (EPI == 2) ? bias[n0 + coll] : 0.f;
#pragma unroll
          for (int r = 0; r < 4; ++r) {
            float v = acc[i][j][r];
            if (EPI == 2) {
              v += bv;
              v = v > 0.f ? v : 0.f;
            }
            smem[(rbase + i * 16 + quad * 4 + r) * 144 + coll] = (__bf16)v;
          }
        }
    }
    __syncthreads();
    for (int p = 0; p < 8; ++p) {
      int row = p * 16 + (tid >> 4);
      int c8 = (tid & 15) * 8;
      *(bf16x8*)(Cv + (size_t)(m0 + half * 128 + row) * NDIM + n0 + c8) =
          *(const bf16x8*)(smem + row * 144 + c8);
    }
  }
}

// ---------------------------------------------------------------- attention (R7, unchanged)
// grid 1024: bh = id&255, qq = id>>8 (same-XCD head pairing). Wave: 32 q-rows (2 chunks).
// S^T = mfma(K,Q): lane owns q=l15 column -> shuffle-free softmax, b64 P-writes.
// O^T = mfma(V,P): lane q=l15 matches lsum; b64 out-stores.
__global__ __launch_bounds__(256) void attn_kernel(const __bf16* __restrict__ qkv,
                                                   const __bf16* __restrict__ vtg,
                                                   const float* __restrict__ norms,
                                                   __bf16* __restrict__ out) {
  __shared__ __align__(16) __bf16 Ks[64 * 64];   // [sk][d]
  __shared__ __align__(16) __bf16 Vs[64 * 64];   // [d][sk]
  __shared__ __align__(16) __bf16 P2[4][16 * 72];
  const int tid = threadIdx.x, wave = tid >> 6, lane = tid & 63;
  const int l15 = lane & 15, quad = lane >> 4;
  const int bh = blockIdx.x & 255;
  const int qq = blockIdx.x >> 8;
  const int b = bh >> 3, h = bh & 7;
  const int qbase = qq * 128 + wave * 32;
  const int rs = lane >> 3;
  const int swz_st = ((lane & 7) ^ rs) * 8;
  const int s7 = l15 & 7;

  const __bf16* Qb = qkv + (size_t)(b * 512) * 1536 + h * 64;
  const __bf16* Kb = Qb + 512;
  const __bf16* Vtb = vtg + (size_t)bh * 32768;
  const float* nkinv = norms + 131072 + bh * 512;
  const float* nqinv = norms + bh * 512;
  __bf16* Pw = P2[wave];

  bf16x8 aq[2][2];
  float cq[2];
  for (int ch = 0; ch < 2; ++ch) {
    int qrow = qbase + ch * 16;
    aq[ch][0] = *(const bf16x8*)(Qb + (size_t)(qrow + l15) * 1536 + quad * 8);
    aq[ch][1] = *(const bf16x8*)(Qb + (size_t)(qrow + l15) * 1536 + 32 + quad * 8);
    cq[ch] = nqinv[qrow + l15] * INV_TEMP;
  }

  floatx4 zero = {0.f, 0.f, 0.f, 0.f};
  floatx4 o[2][4];
  float lsum[2] = {0.f, 0.f};
  for (int ch = 0; ch < 2; ++ch)
    for (int jd = 0; jd < 4; ++jd) o[ch][jd] = zero;

  for (int kt = 0; kt < 8; ++kt) {
    int s0 = kt * 64;
    __syncthreads();
    for (int c = 0; c < 4; ++c) {
      int g = wave * 4 + c;
      const __bf16* src;
      __bf16* dst;
      if (g < 8) {
        int sk = g * 8 + rs;
        src = Kb + (size_t)(s0 + sk) * 1536 + swz_st;
        dst = Ks + g * 512;
      } else {
        int g2 = g - 8;
        int d = g2 * 8 + rs;
        src = Vtb + (size_t)d * 512 + s0 + swz_st;
        dst = Vs + g2 * 512;
      }
      gload_lds16(src, dst + lane * 8);
    }
    __syncthreads();

    for (int ch = 0; ch < 2; ++ch) {
      floatx4 z[4];
      for (int j = 0; j < 4; ++j) {
        int r64 = (j * 16 + l15) * 64;
        bf16x8 k0 = *(const bf16x8*)(Ks + r64 + ((quad ^ s7) * 8));
        bf16x8 k1 = *(const bf16x8*)(Ks + r64 + (((4 + quad) ^ s7) * 8));
        floatx4 zz = zero;
        zz = __builtin_amdgcn_mfma_f32_16x16x32_bf16(k0, aq[ch][0], zz, 0, 0, 0);
        zz = __builtin_amdgcn_mfma_f32_16x16x32_bf16(k1, aq[ch][1], zz, 0, 0, 0);
        z[j] = zz;
      }
      for (int j = 0; j < 4; ++j) {
        floatx4 nk4 = *(const floatx4*)(nkinv + s0 + j * 16 + quad * 4);
        bf16x4 pk;
        for (int r = 0; r < 4; ++r) {
          float p = __expf(z[j][r] * cq[ch] * nk4[r]);
          lsum[ch] += p;
          pk[r] = (__bf16)p;
        }
        *(bf16x4*)(Pw + l15 * 72 + j * 16 + quad * 4) = pk;
      }
      bf16x8 ap0 = *(const bf16x8*)(Pw + l15 * 72 + quad * 8);
      bf16x8 ap1 = *(const bf16x8*)(Pw + l15 * 72 + 32 + quad * 8);
      for (int jd = 0; jd < 4; ++jd) {
        int r64 = (jd * 16 + l15) * 64;
        bf16x8 v0 = *(const bf16x8*)(Vs + r64 + ((quad ^ s7) * 8));
        bf16x8 v1 = *(const bf16x8*)(Vs + r64 + (((4 + quad) ^ s7) * 8));
        o[ch][jd] = __builtin_amdgcn_mfma_f32_16x16x32_bf16(v0, ap0, o[ch][jd], 0, 0, 0);
        o[ch][jd] = __builtin_amdgcn_mfma_f32_16x16x32_bf16(v1, ap1, o[ch][jd], 0, 0, 0);
      }
    }
  }

  for (int ch = 0; ch < 2; ++ch) {
    float s = lsum[ch];
    s += __shfl_xor(s, 16, 64);
    s += __shfl_xor(s, 32, 64);
    float inv = __builtin_amdgcn_rcpf(s);
    int q = qbase + ch * 16 + l15;
    __bf16* op = out + (size_t)(b * 512 + q) * 512 + h * 64;
    for (int jd = 0; jd < 4; ++jd) {
      bf16x4 pk;
      for (int r = 0; r < 4; ++r) pk[r] = (__bf16)(o[ch][jd][r] * inv);
      *(bf16x4*)(op + jd * 16 + quad * 4) = pk;
    }
  }
}

// ---------------------------------------------------------------- residual + layernorm (R7, unchanged)
template <bool X1BF, bool WF, bool WB>
__global__ __launch_bounds__(256) void resid_ln(const float* __restrict__ X1f,
                                                const __bf16* __restrict__ X1b,
                                                const __bf16* __restrict__ X2,
                                                const float* __restrict__ bias,
                                                const float* __restrict__ g,
                                                const float* __restrict__ be,
                                                float* __restrict__ outf,
                                                __bf16* __restrict__ outb) {
  int row = blockIdx.x * 4 + (threadIdx.x >> 6);
  int lane = threadIdx.x & 63;
  float v[8];
  bf16x8 b8 = *(const bf16x8*)(X2 + (size_t)row * 512 + lane * 8);
  if (X1BF) {
    bf16x8 a = *(const bf16x8*)(X1b + (size_t)row * 512 + lane * 8);
    for (int i = 0; i < 8; ++i) v[i] = (float)a[i] + (float)b8[i];
  } else {
    const float4* r1 = (const float4*)(X1f + (size_t)row * 512);
    float4 a0 = r1[lane * 2], a1 = r1[lane * 2 + 1];
    v[0] = a0.x; v[1] = a0.y; v[2] = a0.z; v[3] = a0.w;
    v[4] = a1.x; v[5] = a1.y; v[6] = a1.z; v[7] = a1.w;
    for (int i = 0; i < 8; ++i) v[i] += (float)b8[i];
  }
  if (bias) {
    const float* bp = bias + lane * 8;
    for (int i = 0; i < 8; ++i) v[i] += bp[i];
  }
  float s = 0.f, sq = 0.f;
  for (int i = 0; i < 8; ++i) {
    s += v[i];
    sq += v[i] * v[i];
  }
  for (int m = 1; m < 64; m <<= 1) {
    s += __shfl_xor(s, m, 64);
    sq += __shfl_xor(sq, m, 64);
  }
  float mean = s * (1.f / 512.f);
  float var = sq * (1.f / 512.f) - mean * mean;
  float rstd = rsqrtf(var + LN_EPS);
  const float* gp = g + lane * 8;
  const float* bp2 = be + lane * 8;
  float o[8];
  for (int i = 0; i < 8; ++i) o[i] = (v[i] - mean) * rstd * gp[i] + bp2[i];
  if (WF) {
    float4 w0 = {o[0], o[1], o[2], o[3]}, w1 = {o[4], o[5], o[6], o[7]};
    ((float4*)(outf + (size_t)row * 512))[lane * 2] = w0;
    ((float4*)(outf + (size_t)row * 512))[lane * 2 + 1] = w1;
  }
  if (WB) {
    __bf16 tmp[8];
    for (int i = 0; i < 8; ++i) tmp[i] = (__bf16)o[i];
    *(bf16x8*)(outb + (size_t)row * 512 + lane * 8) = *(bf16x8*)tmp;
  }
}

// ---------------------------------------------------------------- launcher
extern "C" void kernel_launch(void* const* d_in, const int* in_sizes, int n_in,
                              void* d_out, int out_size, void* d_ws, size_t ws_size,
                              hipStream_t stream) {
  const float* x     = (const float*)d_in[0];
  const float* w_q   = (const float*)d_in[1];
  const float* w_k   = (const float*)d_in[2];
  const float* w_v   = (const float*)d_in[3];
  const float* w_o   = (const float*)d_in[4];
  const float* w_ff1 = (const float*)d_in[5];
  const float* b_ff1 = (const float*)d_in[6];
  const float* w_ff2 = (const float*)d_in[7];
  const float* b_ff2 = (const float*)d_in[8];
  const float* g1    = (const float*)d_in[9];
  const float* b1    = (const float*)d_in[10];
  const float* g2    = (const float*)d_in[11];
  const float* b2    = (const float*)d_in[12];
  float* out = (float*)d_out;

  char* ws = (char*)d_ws;
  size_t off = 0;
  auto alloc = [&](size_t bytes) -> void* {
    void* p = ws + off;
    off += (bytes + 255) & ~(size_t)255;
    return p;
  };
  __bf16* xb     = (__bf16*)alloc((size_t)Mrows * 512 * 2);
  __bf16* wt_qkv = (__bf16*)alloc((size_t)1536 * 512 * 2);
  __bf16* wt_o   = (__bf16*)alloc((size_t)512 * 512 * 2);
  __bf16* wt_ff1 = (__bf16*)alloc((size_t)2048 * 512 * 2);
  __bf16* wt_ff2 = (__bf16*)alloc((size_t)512 * 2048 * 2);
  __bf16* qkv    = (__bf16*)alloc((size_t)Mrows * 1536 * 2);
  float*  norms  = (float*)alloc((size_t)262144 * 4);
  __bf16* attn   = (__bf16*)alloc((size_t)Mrows * 512 * 2);
  __bf16* projb  = (__bf16*)alloc((size_t)Mrows * 512 * 2);
  __bf16* h1b    = (__bf16*)alloc((size_t)Mrows * 512 * 2);
  __bf16* mid    = (__bf16*)alloc((size_t)Mrows * 2048 * 2);
  __bf16* vtg    = mid;            // alias: dead before ff1 writes mid
  __bf16* f2o    = attn;           // alias: attn dead after w_o GEMM

  prep_kernel<<<8960, 256, 0, stream>>>(x, xb, w_q, w_k, w_v, w_o, w_ff1, w_ff2,
                                        wt_qkv, wt_qkv + 512 * 512, wt_qkv + 2 * 512 * 512,
                                        wt_o, wt_ff1, wt_ff2);

  // QKV (fused inverse norms + V-transpose into vtg), MT=2: 64 m-tiles x 12 n
  gemm_bt<4, 2, 12, 1536, 512><<<dim3(12 * 64), 256, 0, stream>>>(xb, wt_qkv, qkv, nullptr,
                                                                  norms, vtg);
  attn_kernel<<<dim3(1024), 256, 0, stream>>>(qkv, vtg, norms, attn);
  // w_o proj -> bf16 (MT=1, 512 blocks = 2/CU)
  gemm_bt<0, 1, 4, 512, 512><<<dim3(4 * 128), 256, 0, stream>>>(attn, wt_o, projb, nullptr,
                                                                nullptr, nullptr);
  // LN1: x + projb -> h1b (bf16)
  resid_ln<false, false, true><<<4096, 256, 0, stream>>>(x, nullptr, projb, nullptr,
                                                         g1, b1, nullptr, h1b);
  // FFN1 (+bias, relu), MT=2: 64 m-tiles x 16 n
  gemm_bt<2, 2, 16, 2048, 512><<<dim3(16 * 64), 256, 0, stream>>>(h1b, wt_ff1, mid, b_ff1,
                                                                  nullptr, nullptr);
  // FFN2 -> bf16 (bias folded into LN2), MT=1
  gemm_bt<0, 1, 4, 512, 2048><<<dim3(4 * 128), 256, 0, stream>>>(mid, wt_ff2, f2o, nullptr,
                                                                 nullptr, nullptr);
  // LN2: h1b + f2o + b_ff2 -> out (f32)
  resid_ln<true, true, false><<<4096, 256, 0, stream>>>(nullptr, h1b, f2o, b_ff2,
                                                        g2, b2, out, nullptr);
}